// Round 5
// baseline (651.741 us; speedup 1.0000x reference)
//
#include <hip/hip_runtime.h>
#include <stdint.h>

// ---------- types ----------
typedef __attribute__((ext_vector_type(4))) float f32x4;
typedef __attribute__((ext_vector_type(8))) __bf16 bf8_t;     // MFMA A/B fragment (8 bf16 = 4 VGPR)
typedef __attribute__((ext_vector_type(8))) uint16_t u16x8;   // raw 16B bf16 load/store

typedef __attribute__((address_space(1))) uint8_t as1_u8;
typedef __attribute__((address_space(3))) uint8_t as3_u8;

__device__ inline void async_copy16(const void* g, void* l) {
  __builtin_amdgcn_global_load_lds((const as1_u8*)g, (as3_u8*)l, 16, 0, 0);
}

__device__ inline uint16_t f2bf(float f) {
  uint32_t u = __builtin_bit_cast(uint32_t, f);
  u = (u + 0x7fff + ((u >> 16) & 1)) >> 16;
  return (uint16_t)u;
}
__device__ inline float bf2f(uint16_t h) {
  uint32_t u = ((uint32_t)h) << 16;
  return __builtin_bit_cast(float, u);
}
// XOR swizzle for 256B-row bf16 LDS tiles (16 chunks of 16B per row)
__device__ inline int swz(int r) { return (((r & 7) ^ ((r >> 3) & 7)) << 4); }
// XOR swizzle for 128B-row bf16 LDS tiles (8 chunks of 16B per row)
__device__ inline int vswz(int r) { return ((r & 7) << 4); }

// ---------- rmsnorm: f32 [2048] row -> bf16 ----------
__global__ __launch_bounds__(256) void rmsnorm_kernel(const float* __restrict__ X,
                                                      const float* __restrict__ S,
                                                      uint16_t* __restrict__ O) {
  const int row = blockIdx.x;
  const int tid = threadIdx.x;
  const float* xr = X + (size_t)row * 2048;
  float4 v1 = ((const float4*)xr)[tid * 2];
  float4 v2 = ((const float4*)xr)[tid * 2 + 1];
  float ss = v1.x * v1.x + v1.y * v1.y + v1.z * v1.z + v1.w * v1.w +
             v2.x * v2.x + v2.y * v2.y + v2.z * v2.z + v2.w * v2.w;
  #pragma unroll
  for (int m = 1; m < 64; m <<= 1) ss += __shfl_xor(ss, m);
  __shared__ float wsum[4];
  if ((tid & 63) == 0) wsum[tid >> 6] = ss;
  __syncthreads();
  float tot = wsum[0] + wsum[1] + wsum[2] + wsum[3];
  float inv = rsqrtf(tot * (1.0f / 2048.0f) + 1e-5f);
  const int base = tid * 8;
  const float* sc = S + base;
  float xs[8] = {v1.x, v1.y, v1.z, v1.w, v2.x, v2.y, v2.z, v2.w};
  u16x8 o;
  #pragma unroll
  for (int j = 0; j < 8; j++) o[j] = f2bf(xs[j] * inv * sc[j]);
  *(u16x8*)(O + (size_t)row * 2048 + base) = o;
}

// ---------- transpose+convert: W f32 [K][N] -> WT bf16 [N][K], 64x64 tiles ----------
__global__ __launch_bounds__(256) void transpose_conv(const float* __restrict__ W,
                                                      uint16_t* __restrict__ WT,
                                                      int K, int N) {
  __shared__ float tile[64][65];
  const int n0 = blockIdx.x * 64, k0 = blockIdx.y * 64;
  const int tid = threadIdx.x;
  const int lr = tid >> 4;
  const int lc = (tid & 15) * 4;
  #pragma unroll
  for (int i = 0; i < 4; i++) {
    const float4 v = *(const float4*)&W[(size_t)(k0 + lr + i * 16) * N + n0 + lc];
    tile[lr + i * 16][lc] = v.x;
    tile[lr + i * 16][lc + 1] = v.y;
    tile[lr + i * 16][lc + 2] = v.z;
    tile[lr + i * 16][lc + 3] = v.w;
  }
  __syncthreads();
  const int tn = tid >> 3;
  const int tk = (tid & 7) * 8;
  #pragma unroll
  for (int i = 0; i < 2; i++) {
    u16x8 o;
    #pragma unroll
    for (int j = 0; j < 8; j++) o[j] = f2bf(tile[tk + j][tn + i * 32]);
    *(u16x8*)&WT[(size_t)(n0 + tn + i * 32) * K + k0 + tk] = o;
  }
}

// ---------- transpose V third of qkv: bf16 [2048 t][4096+c] -> vT [2048 c][2048 t] ----------
__global__ __launch_bounds__(256) void transpose_v(const uint16_t* __restrict__ qkv,
                                                   uint16_t* __restrict__ vT) {
  __shared__ uint16_t tile[64][68];
  const int t0 = blockIdx.x * 64;
  const int c0 = blockIdx.y * 64;
  const int tid = threadIdx.x;
  const int lr = tid >> 3;
  const int lc = (tid & 7) * 8;
  #pragma unroll
  for (int i = 0; i < 2; i++) {
    const int r = lr + i * 32;
    u16x8 v = *(const u16x8*)&qkv[(size_t)(t0 + r) * 6144 + 4096 + c0 + lc];
    #pragma unroll
    for (int j = 0; j < 8; j++) tile[lc + j][r] = v[j];
  }
  __syncthreads();
  #pragma unroll
  for (int i = 0; i < 2; i++) {
    const int c = lr + i * 32;
    u16x8 o = *(const u16x8*)&tile[c][lc];
    *(u16x8*)&vT[(size_t)(c0 + c) * 2048 + t0 + lc] = o;
  }
}

// ---------- GEMM epilogue modes ----------
enum { EPI_BF16 = 0, EPI_ADDF32 = 1, EPI_SILUMUL = 2 };

// ---------- 128x128 m97-structure GEMM (proj / mlp_proj) ----------
template <int EPI>
__global__ __launch_bounds__(256, 2) void gemm_bt(const uint16_t* __restrict__ A,
                                                  const uint16_t* __restrict__ BT,
                                                  void* __restrict__ Cout,
                                                  const void* __restrict__ RES,
                                                  int M, int N, int K) {
  __shared__ uint16_t As[128 * 32];
  __shared__ uint16_t Bs[128 * 32];
  const int tid = threadIdx.x;
  const int lane = tid & 63;
  const int w = tid >> 6;
  const int l15 = lane & 15, l4 = lane >> 4;
  const int m0 = blockIdx.y * 128, n0 = blockIdx.x * 128;
  const int wr = w >> 1, wc = w & 1;

  f32x4 acc[4][4];
  #pragma unroll
  for (int i = 0; i < 4; i++)
    #pragma unroll
    for (int j = 0; j < 4; j++) acc[i][j] = 0.0f;

  for (int kk = 0; kk < K; kk += 32) {
    __syncthreads();
    #pragma unroll
    for (int s = 0; s < 2; s++) {
      const int bu = s * 256 + w * 64;
      const int unit = bu + lane;
      const int row = unit >> 2, ch = unit & 3;
      async_copy16(A + (size_t)(m0 + row) * K + kk + ch * 8, (char*)As + bu * 16);
      async_copy16(BT + (size_t)(n0 + row) * K + kk + ch * 8, (char*)Bs + bu * 16);
    }
    __syncthreads();
    bf8_t a[4], b[4];
    #pragma unroll
    for (int mi = 0; mi < 4; mi++)
      a[mi] = *(const bf8_t*)(As + (wr * 64 + mi * 16 + l15) * 32 + l4 * 8);
    #pragma unroll
    for (int ni = 0; ni < 4; ni++)
      b[ni] = *(const bf8_t*)(Bs + (wc * 64 + ni * 16 + l15) * 32 + l4 * 8);
    #pragma unroll
    for (int mi = 0; mi < 4; mi++)
      #pragma unroll
      for (int ni = 0; ni < 4; ni++)
        acc[mi][ni] = __builtin_amdgcn_mfma_f32_16x16x32_bf16(a[mi], b[ni], acc[mi][ni], 0, 0, 0);
  }

  #pragma unroll
  for (int mi = 0; mi < 4; mi++) {
    #pragma unroll
    for (int ni = 0; ni < 4; ni++) {
      #pragma unroll
      for (int r = 0; r < 4; r++) {
        const int row = m0 + wr * 64 + mi * 16 + l4 * 4 + r;
        const int col = n0 + wc * 64 + ni * 16 + l15;
        const size_t idx = (size_t)row * N + col;
        const float v = acc[mi][ni][r];
        if (EPI == EPI_BF16) {
          ((uint16_t*)Cout)[idx] = f2bf(v);
        } else if (EPI == EPI_ADDF32) {
          ((float*)Cout)[idx] = ((const float*)RES)[idx] + v;
        } else {
          const float g = bf2f(((const uint16_t*)RES)[idx]);
          const float sg = g / (1.0f + __expf(-g));
          ((uint16_t*)Cout)[idx] = f2bf(sg * v);
        }
      }
    }
  }
}

// ---------- 256x256 8-phase GEMM (T2+T3+T4+T5, plain HIP) ----------
// 8 waves (2M x 4N), BK=64. LDS = 2 bufs x {A 32KB + B 32KB} = 128 KB, organized
// as 16KB quarter-regions: A[mh][wm-block][64][64], B[nh][wn-block][32][64]
// (rows permuted so quadrant (mh,nh) reads exactly regions A[mh], B[nh]).
// Region r of K-tile T+2 is staged in the phase right after r's last reader
// phase for K-tile T (WAR edge = the inter-phase barrier); counted vmcnt(4)
// at phases 4/8 guarantees regions land >=4 phases before first read.
// NO __syncthreads (would drain vmcnt to 0); raw s_barrier only.
#define PHASE(TT, MH, NH, STAGE, VMASM)                                            \
  {                                                                                \
    const int bb = (TT) & 1;                                                       \
    bf8_t af[4][2], bfr[2][2];                                                     \
    const char* Ab = (const char*)&Alds[bb][MH][wm][0][0];                         \
    const char* Bb = (const char*)&Blds[bb][NH][wn][0][0];                         \
    _Pragma("unroll") for (int mi = 0; mi < 4; mi++)                               \
      _Pragma("unroll") for (int ks = 0; ks < 2; ks++)                             \
        af[mi][ks] = *(const bf8_t*)(Ab + (mi * 16 + l15) * 128 +                  \
                                     (((ks * 4 + l4) ^ swz8) * 16));               \
    _Pragma("unroll") for (int ni = 0; ni < 2; ni++)                               \
      _Pragma("unroll") for (int ks = 0; ks < 2; ks++)                             \
        bfr[ni][ks] = *(const bf8_t*)(Bb + (ni * 16 + l15) * 128 +                 \
                                      (((ks * 4 + l4) ^ swz8) * 16));              \
    STAGE;                                                                         \
    VMASM;                                                                         \
    __builtin_amdgcn_s_barrier();                                                  \
    __builtin_amdgcn_s_setprio(1);                                                 \
    _Pragma("unroll") for (int mi = 0; mi < 4; mi++)                               \
      _Pragma("unroll") for (int ni = 0; ni < 2; ni++)                             \
        _Pragma("unroll") for (int ks = 0; ks < 2; ks++)                           \
          acc[(MH)*4 + mi][(NH)*2 + ni] = __builtin_amdgcn_mfma_f32_16x16x32_bf16( \
              af[mi][ks], bfr[ni][ks], acc[(MH)*4 + mi][(NH)*2 + ni], 0, 0, 0);    \
    __builtin_amdgcn_s_setprio(0);                                                 \
    __builtin_amdgcn_sched_barrier(0);                                             \
    __builtin_amdgcn_s_barrier();                                                  \
  }

template <int EPI>
__global__ __launch_bounds__(512, 2) void gemm8p(const uint16_t* __restrict__ A,
                                                 const uint16_t* __restrict__ BT,
                                                 void* __restrict__ Cout,
                                                 const void* __restrict__ RES,
                                                 int M, int N, int K) {
  __shared__ uint16_t Alds[2][2][2][64][64];  // [buf][mh][wm][row][col]
  __shared__ uint16_t Blds[2][2][4][32][64];  // [buf][nh][wn][row][col]
  const int tid = threadIdx.x;
  const int lane = tid & 63;
  const int w = tid >> 6;
  const int l15 = lane & 15, l4 = lane >> 4;
  const int swz8 = l15 & 7;
  const int wm = w >> 2, wn = w & 3;  // 2 x 4 wave grid
  const int m0 = blockIdx.y * 256, n0 = blockIdx.x * 256;

  f32x4 acc[8][4];
  #pragma unroll
  for (int i = 0; i < 8; i++)
    #pragma unroll
    for (int j = 0; j < 4; j++) acc[i][j] = 0.0f;

  // Stage A-region mh of K-tile T (16KB: rows {wm*128+mh*64 ..+64} for both wm).
  // LDS dest linear; source k-chunk pre-swizzled (rule 21).
  auto stageA = [&](int T, int mh) {
    const int b = T & 1;
    const int kt = T << 6;
    #pragma unroll
    for (int i = 0; i < 2; i++) {
      const int ub = i * 512 + w * 64;       // wave-uniform chunk base
      const int u = ub + lane;
      const int wmb = u >> 9;
      const int rowin = (u >> 3) & 63;
      const int c = (u & 7) ^ (rowin & 7);
      async_copy16(A + (size_t)(m0 + wmb * 128 + mh * 64 + rowin) * K + kt + c * 8,
                   (char*)&Alds[b][mh][0][0][0] + ub * 16);
    }
  };
  // Stage B-region nh of K-tile T (16KB: rows {wn*64+nh*32 ..+32} for all wn).
  auto stageB = [&](int T, int nh) {
    const int b = T & 1;
    const int kt = T << 6;
    #pragma unroll
    for (int i = 0; i < 2; i++) {
      const int ub = i * 512 + w * 64;
      const int u = ub + lane;
      const int wnb = u >> 8;
      const int rowin = (u >> 3) & 31;
      const int c = (u & 7) ^ (rowin & 7);
      async_copy16(BT + (size_t)(n0 + wnb * 64 + nh * 32 + rowin) * K + kt + c * 8,
                   (char*)&Blds[b][nh][0][0][0] + ub * 16);
    }
  };

  // prologue: tile0 fully (A0,B0,A1,B1 -> buf0) + tile1 A0,B0 -> buf1
  stageA(0, 0); stageB(0, 0); stageA(0, 1); stageB(0, 1);
  stageA(1, 0); stageB(1, 0);
  asm volatile("s_waitcnt vmcnt(4)" ::: "memory");  // tile0 landed; tile1 half in flight
  __builtin_amdgcn_s_barrier();

  const int NT = K >> 6;
  const int NJ = NT >> 1;
  for (int j = 0; j < NJ - 1; ++j) {
    const int t0 = 2 * j, t1 = t0 + 1, t2 = t0 + 2, t3 = t0 + 3;
    PHASE(t0, 0, 0, stageA(t1, 1), );
    PHASE(t0, 0, 1, stageB(t1, 1), );
    PHASE(t0, 1, 0, stageA(t2, 0), );
    PHASE(t0, 1, 1, stageB(t2, 0), asm volatile("s_waitcnt vmcnt(4)" ::: "memory"));
    PHASE(t1, 0, 0, stageA(t2, 1), );
    PHASE(t1, 0, 1, stageB(t2, 1), );
    PHASE(t1, 1, 0, stageA(t3, 0), );
    PHASE(t1, 1, 1, stageB(t3, 0), asm volatile("s_waitcnt vmcnt(4)" ::: "memory"));
  }
  {  // peeled last iter: only A1/B1 of the final tile remain to stage; the
     // counted vmcnt(4) would under-count here (stage slots skipped) -> vmcnt(0).
    const int t0 = NT - 2, t1 = NT - 1;
    PHASE(t0, 0, 0, stageA(t1, 1), );
    PHASE(t0, 0, 1, stageB(t1, 1), );
    PHASE(t0, 1, 0, , );
    PHASE(t0, 1, 1, , asm volatile("s_waitcnt vmcnt(0)" ::: "memory"));
    PHASE(t1, 0, 0, , );
    PHASE(t1, 0, 1, , );
    PHASE(t1, 1, 0, , );
    PHASE(t1, 1, 1, , );
  }

  // epilogue
  #pragma unroll
  for (int ai = 0; ai < 8; ai++) {
    #pragma unroll
    for (int bj = 0; bj < 4; bj++) {
      const int row0 = m0 + wm * 128 + (ai >> 2) * 64 + (ai & 3) * 16 + l4 * 4;
      const int col = n0 + wn * 64 + (bj >> 1) * 32 + (bj & 1) * 16 + l15;
      #pragma unroll
      for (int r = 0; r < 4; r++) {
        const size_t idx = (size_t)(row0 + r) * N + col;
        const float v = acc[ai][bj][r];
        if (EPI == EPI_BF16) {
          ((uint16_t*)Cout)[idx] = f2bf(v);
        } else if (EPI == EPI_ADDF32) {
          ((float*)Cout)[idx] = ((const float*)RES)[idx] + v;
        } else {
          const float g = bf2f(((const uint16_t*)RES)[idx]);
          const float sg = g / (1.0f + __expf(-g));
          ((uint16_t*)Cout)[idx] = f2bf(sg * v);
        }
      }
    }
  }
}

// ---------- flash attention with alibi + causal (unchanged) ----------
__global__ __launch_bounds__(256, 2) void attn_kernel(const uint16_t* __restrict__ qkv,
                                                      const uint16_t* __restrict__ vT,
                                                      const float* __restrict__ alibi,
                                                      uint16_t* __restrict__ Y) {
  const int h = blockIdx.y;
  const int qt = 31 - blockIdx.x;
  const int tid = threadIdx.x;
  const int lane = tid & 63;
  const int w = tid >> 6;
  const int l15 = lane & 15, l4 = lane >> 4;

  __shared__ uint16_t Ks[2][64 * 128];
  __shared__ uint16_t Vs[2][128 * 64];
  __shared__ uint16_t Ps[4][16 * 64];

  const float scale = 0.08838834764831845f;

  auto stage = [&](int kv0, int b) {
    #pragma unroll
    for (int i = 0; i < 4; i++) {
      const int u = tid + i * 256;
      const int r = u >> 4;
      const int c = (u & 15) ^ ((r & 7) ^ ((r >> 3) & 7));
      async_copy16(qkv + (size_t)(kv0 + r) * 6144 + 2048 + h * 128 + c * 8,
                   (char*)Ks[b] + u * 16);
    }
    #pragma unroll
    for (int i = 0; i < 4; i++) {
      const int u = tid + i * 256;
      const int r = u >> 3;
      const int c = (u & 7) ^ (r & 7);
      async_copy16(vT + (size_t)(h * 128 + r) * 2048 + kv0 + c * 8,
                   (char*)Vs[b] + u * 16);
    }
  };
  auto load_al = [&](int kv0, float (&al)[4][4]) {
    #pragma unroll
    for (int r = 0; r < 4; r++) {
      const size_t rowb = ((size_t)h * 2048 + (qt * 64 + w * 16 + l4 * 4 + r)) * 2048;
      #pragma unroll
      for (int nf = 0; nf < 4; nf++)
        al[nf][r] = alibi[rowb + kv0 + nf * 16 + l15];
    }
  };

  const int qrow = qt * 64 + w * 16 + l15;
  bf8_t qf[4];
  #pragma unroll
  for (int kc = 0; kc < 4; kc++)
    qf[kc] = *(const bf8_t*)(qkv + (size_t)qrow * 6144 + h * 128 + kc * 32 + l4 * 8);

  f32x4 accy[8];
  #pragma unroll
  for (int i = 0; i < 8; i++) accy[i] = 0.0f;
  float mrun[4], lrun[4];
  #pragma unroll
  for (int r = 0; r < 4; r++) { mrun[r] = -1e30f; lrun[r] = 0.0f; }

  stage(0, 0);
  float al[4][4];
  load_al(0, al);

  for (int kvt = 0; kvt <= qt; kvt++) {
    const int b = kvt & 1;
    const int kv0 = kvt * 64;
    __syncthreads();

    const int kvn = (kvt < qt) ? (kvt + 1) : qt;
    float aln[4][4];
    load_al(kvn * 64, aln);
    stage(kvn * 64, b ^ 1);

    float s[4][4];
    #pragma unroll
    for (int nf = 0; nf < 4; nf++) {
      f32x4 sa = 0.0f;
      const int krow = nf * 16 + l15;
      #pragma unroll
      for (int kc = 0; kc < 4; kc++) {
        bf8_t kb = *(const bf8_t*)((const char*)Ks[b] +
                                   ((krow * 256 + kc * 64 + l4 * 16) ^ swz(krow)));
        sa = __builtin_amdgcn_mfma_f32_16x16x32_bf16(qf[kc], kb, sa, 0, 0, 0);
      }
      const int kvcol = kv0 + nf * 16 + l15;
      #pragma unroll
      for (int r = 0; r < 4; r++) {
        const int q = qt * 64 + w * 16 + l4 * 4 + r;
        float sv = sa[r] * scale + al[nf][r];
        if (kvcol > q) sv = -1e30f;
        s[nf][r] = sv;
      }
    }

    #pragma unroll
    for (int r = 0; r < 4; r++) {
      float rm = fmaxf(fmaxf(s[0][r], s[1][r]), fmaxf(s[2][r], s[3][r]));
      rm = fmaxf(rm, __shfl_xor(rm, 1));
      rm = fmaxf(rm, __shfl_xor(rm, 2));
      rm = fmaxf(rm, __shfl_xor(rm, 4));
      rm = fmaxf(rm, __shfl_xor(rm, 8));
      const float mnew = fmaxf(mrun[r], rm);
      const float alpha = __expf(mrun[r] - mnew);
      mrun[r] = mnew;
      float rs = 0.0f;
      #pragma unroll
      for (int nf = 0; nf < 4; nf++) {
        const float p = __expf(s[nf][r] - mnew);
        s[nf][r] = p;
        rs += p;
      }
      rs += __shfl_xor(rs, 1);
      rs += __shfl_xor(rs, 2);
      rs += __shfl_xor(rs, 4);
      rs += __shfl_xor(rs, 8);
      lrun[r] = lrun[r] * alpha + rs;
      #pragma unroll
      for (int df = 0; df < 8; df++) accy[df][r] *= alpha;
    }

    #pragma unroll
    for (int nf = 0; nf < 4; nf++) {
      #pragma unroll
      for (int r = 0; r < 4; r++) {
        const int rq = l4 * 4 + r;
        const int bo = (rq * 128 + (nf * 16 + l15) * 2) ^ vswz(rq);
        *(uint16_t*)((char*)Ps[w] + bo) = f2bf(s[nf][r]);
      }
    }

    #pragma unroll
    for (int kk = 0; kk < 2; kk++) {
      bf8_t pa = *(const bf8_t*)((const char*)Ps[w] +
                                 ((l15 * 128 + kk * 64 + l4 * 16) ^ vswz(l15)));
      #pragma unroll
      for (int df = 0; df < 8; df++) {
        const int vr = df * 16 + l15;
        bf8_t vb = *(const bf8_t*)((const char*)Vs[b] +
                                   ((vr * 128 + kk * 64 + l4 * 16) ^ vswz(vr)));
        accy[df] = __builtin_amdgcn_mfma_f32_16x16x32_bf16(pa, vb, accy[df], 0, 0, 0);
      }
    }

    #pragma unroll
    for (int nf = 0; nf < 4; nf++)
      #pragma unroll
      for (int r = 0; r < 4; r++) al[nf][r] = aln[nf][r];
  }

  #pragma unroll
  for (int df = 0; df < 8; df++) {
    #pragma unroll
    for (int r = 0; r < 4; r++) {
      const int row = qt * 64 + w * 16 + l4 * 4 + r;
      const int col = h * 128 + df * 16 + l15;
      Y[(size_t)row * 2048 + col] = f2bf(accy[df][r] / lrun[r]);
    }
  }
}

// ---------- launch ----------
extern "C" void kernel_launch(void* const* d_in, const int* in_sizes, int n_in,
                              void* d_out, int out_size, void* d_ws, size_t ws_size,
                              hipStream_t stream) {
  const float* x      = (const float*)d_in[0];
  const float* alibi  = (const float*)d_in[1];
  const float* w_attn = (const float*)d_in[2];
  const float* w_proj = (const float*)d_in[3];
  const float* w_fc1  = (const float*)d_in[4];
  const float* w_fc2  = (const float*)d_in[5];
  const float* w_mp   = (const float*)d_in[6];
  const float* rms1   = (const float*)d_in[7];
  const float* rms2   = (const float*)d_in[8];
  float* out = (float*)d_out;

  char* ws = (char*)d_ws;
  uint16_t* xn      = (uint16_t*)(ws + 0);
  uint16_t* qkv     = (uint16_t*)(ws + 8388608);
  uint16_t* y       = (uint16_t*)(ws + 33554432);
  uint16_t* g1      = (uint16_t*)(ws + 41943040);
  uint16_t* hbuf    = (uint16_t*)(ws + 65011712);
  uint16_t* wt_attn = (uint16_t*)(ws + 88080384);
  uint16_t* wt_proj = (uint16_t*)(ws + 113246208);
  uint16_t* wt_fc1  = (uint16_t*)(ws + 121634816);
  uint16_t* wt_fc2  = (uint16_t*)(ws + 144703488);
  uint16_t* wt_mp   = (uint16_t*)(ws + 167772160);
  uint16_t* vT      = (uint16_t*)(ws + 190840832);

  transpose_conv<<<dim3(6144 / 64, 2048 / 64), 256, 0, stream>>>(w_attn, wt_attn, 2048, 6144);
  transpose_conv<<<dim3(2048 / 64, 2048 / 64), 256, 0, stream>>>(w_proj, wt_proj, 2048, 2048);
  transpose_conv<<<dim3(5632 / 64, 2048 / 64), 256, 0, stream>>>(w_fc1, wt_fc1, 2048, 5632);
  transpose_conv<<<dim3(5632 / 64, 2048 / 64), 256, 0, stream>>>(w_fc2, wt_fc2, 2048, 5632);
  transpose_conv<<<dim3(2048 / 64, 5632 / 64), 256, 0, stream>>>(w_mp, wt_mp, 5632, 2048);

  rmsnorm_kernel<<<2048, 256, 0, stream>>>(x, rms1, xn);

  gemm8p<EPI_BF16><<<dim3(6144 / 256, 2048 / 256), 512, 0, stream>>>(
      xn, wt_attn, qkv, nullptr, 2048, 6144, 2048);

  transpose_v<<<dim3(32, 32), 256, 0, stream>>>(qkv, vT);

  attn_kernel<<<dim3(32, 16), 256, 0, stream>>>(qkv, vT, alibi, y);

  gemm_bt<EPI_ADDF32><<<dim3(2048 / 128, 2048 / 128), 256, 0, stream>>>(
      y, wt_proj, out, x, 2048, 2048, 2048);

  rmsnorm_kernel<<<2048, 256, 0, stream>>>(out, rms2, xn);

  gemm8p<EPI_BF16><<<dim3(5632 / 256, 2048 / 256), 512, 0, stream>>>(
      xn, wt_fc1, g1, nullptr, 2048, 5632, 2048);

  gemm8p<EPI_SILUMUL><<<dim3(5632 / 256, 2048 / 256), 512, 0, stream>>>(
      xn, wt_fc2, hbuf, g1, 2048, 5632, 2048);

  gemm_bt<EPI_ADDF32><<<dim3(2048 / 128, 2048 / 128), 256, 0, stream>>>(
      hbuf, wt_mp, out, out, 2048, 2048, 5632);
}

// Round 6
// 563.861 us; speedup vs baseline: 1.1559x; 1.1559x over previous
//
#include <hip/hip_runtime.h>
#include <stdint.h>

// ---------- types ----------
typedef __attribute__((ext_vector_type(4))) float f32x4;
typedef __attribute__((ext_vector_type(8))) __bf16 bf8_t;     // MFMA A/B fragment (8 bf16 = 4 VGPR)
typedef __attribute__((ext_vector_type(8))) uint16_t u16x8;   // raw 16B bf16 load/store

typedef __attribute__((address_space(1))) uint8_t as1_u8;
typedef __attribute__((address_space(3))) uint8_t as3_u8;

__device__ inline void async_copy16(const void* g, void* l) {
  __builtin_amdgcn_global_load_lds((const as1_u8*)g, (as3_u8*)l, 16, 0, 0);
}

__device__ inline uint16_t f2bf(float f) {
  uint32_t u = __builtin_bit_cast(uint32_t, f);
  u = (u + 0x7fff + ((u >> 16) & 1)) >> 16;
  return (uint16_t)u;
}
__device__ inline float bf2f(uint16_t h) {
  uint32_t u = ((uint32_t)h) << 16;
  return __builtin_bit_cast(float, u);
}
// XOR swizzle for 256B-row bf16 LDS tiles (16 chunks of 16B per row)
__device__ inline int swz(int r) { return (((r & 7) ^ ((r >> 3) & 7)) << 4); }
// XOR swizzle for 128B-row bf16 LDS tiles (8 chunks of 16B per row)
__device__ inline int vswz(int r) { return ((r & 7) << 4); }

// ---------- rmsnorm: f32 [2048] row -> bf16 ----------
__global__ __launch_bounds__(256) void rmsnorm_kernel(const float* __restrict__ X,
                                                      const float* __restrict__ S,
                                                      uint16_t* __restrict__ O) {
  const int row = blockIdx.x;
  const int tid = threadIdx.x;
  const float* xr = X + (size_t)row * 2048;
  float4 v1 = ((const float4*)xr)[tid * 2];
  float4 v2 = ((const float4*)xr)[tid * 2 + 1];
  float ss = v1.x * v1.x + v1.y * v1.y + v1.z * v1.z + v1.w * v1.w +
             v2.x * v2.x + v2.y * v2.y + v2.z * v2.z + v2.w * v2.w;
  #pragma unroll
  for (int m = 1; m < 64; m <<= 1) ss += __shfl_xor(ss, m);
  __shared__ float wsum[4];
  if ((tid & 63) == 0) wsum[tid >> 6] = ss;
  __syncthreads();
  float tot = wsum[0] + wsum[1] + wsum[2] + wsum[3];
  float inv = rsqrtf(tot * (1.0f / 2048.0f) + 1e-5f);
  const int base = tid * 8;
  const float* sc = S + base;
  float xs[8] = {v1.x, v1.y, v1.z, v1.w, v2.x, v2.y, v2.z, v2.w};
  u16x8 o;
  #pragma unroll
  for (int j = 0; j < 8; j++) o[j] = f2bf(xs[j] * inv * sc[j]);
  *(u16x8*)(O + (size_t)row * 2048 + base) = o;
}

// ---------- transpose+convert: W f32 [K][N] -> WT bf16 [N][K], 64x64 tiles ----------
__global__ __launch_bounds__(256) void transpose_conv(const float* __restrict__ W,
                                                      uint16_t* __restrict__ WT,
                                                      int K, int N) {
  __shared__ float tile[64][65];
  const int n0 = blockIdx.x * 64, k0 = blockIdx.y * 64;
  const int tid = threadIdx.x;
  const int lr = tid >> 4;
  const int lc = (tid & 15) * 4;
  #pragma unroll
  for (int i = 0; i < 4; i++) {
    const float4 v = *(const float4*)&W[(size_t)(k0 + lr + i * 16) * N + n0 + lc];
    tile[lr + i * 16][lc] = v.x;
    tile[lr + i * 16][lc + 1] = v.y;
    tile[lr + i * 16][lc + 2] = v.z;
    tile[lr + i * 16][lc + 3] = v.w;
  }
  __syncthreads();
  const int tn = tid >> 3;
  const int tk = (tid & 7) * 8;
  #pragma unroll
  for (int i = 0; i < 2; i++) {
    u16x8 o;
    #pragma unroll
    for (int j = 0; j < 8; j++) o[j] = f2bf(tile[tk + j][tn + i * 32]);
    *(u16x8*)&WT[(size_t)(n0 + tn + i * 32) * K + k0 + tk] = o;
  }
}

// ---------- transpose V third of qkv: bf16 [2048 t][4096+c] -> vT [2048 c][2048 t] ----------
__global__ __launch_bounds__(256) void transpose_v(const uint16_t* __restrict__ qkv,
                                                   uint16_t* __restrict__ vT) {
  __shared__ uint16_t tile[64][68];
  const int t0 = blockIdx.x * 64;
  const int c0 = blockIdx.y * 64;
  const int tid = threadIdx.x;
  const int lr = tid >> 3;
  const int lc = (tid & 7) * 8;
  #pragma unroll
  for (int i = 0; i < 2; i++) {
    const int r = lr + i * 32;
    u16x8 v = *(const u16x8*)&qkv[(size_t)(t0 + r) * 6144 + 4096 + c0 + lc];
    #pragma unroll
    for (int j = 0; j < 8; j++) tile[lc + j][r] = v[j];
  }
  __syncthreads();
  #pragma unroll
  for (int i = 0; i < 2; i++) {
    const int c = lr + i * 32;
    u16x8 o = *(const u16x8*)&tile[c][lc];
    *(u16x8*)&vT[(size_t)(c0 + c) * 2048 + t0 + lc] = o;
  }
}

// ---------- GEMM epilogue modes ----------
enum { EPI_BF16 = 0, EPI_ADDF32 = 1, EPI_SILUMUL = 2 };

__device__ inline void gemm_epi(int EPI, void* Cout, const void* RES, size_t idx, float v) {
  if (EPI == EPI_BF16) {
    ((uint16_t*)Cout)[idx] = f2bf(v);
  } else if (EPI == EPI_ADDF32) {
    ((float*)Cout)[idx] = ((const float*)RES)[idx] + v;
  } else {
    const float g = bf2f(((const uint16_t*)RES)[idx]);
    const float sg = g / (1.0f + __expf(-g));
    ((uint16_t*)Cout)[idx] = f2bf(sg * v);
  }
}

// ---------- 128x128 m97-structure GEMM (large-N GEMMs: qkv / fc1 / fc2) ----------
template <int EPI>
__global__ __launch_bounds__(256, 2) void gemm_bt(const uint16_t* __restrict__ A,
                                                  const uint16_t* __restrict__ BT,
                                                  void* __restrict__ Cout,
                                                  const void* __restrict__ RES,
                                                  int M, int N, int K) {
  __shared__ uint16_t As[128 * 32];
  __shared__ uint16_t Bs[128 * 32];
  const int tid = threadIdx.x;
  const int lane = tid & 63;
  const int w = tid >> 6;
  const int l15 = lane & 15, l4 = lane >> 4;
  const int m0 = blockIdx.y * 128, n0 = blockIdx.x * 128;
  const int wr = w >> 1, wc = w & 1;

  f32x4 acc[4][4];
  #pragma unroll
  for (int i = 0; i < 4; i++)
    #pragma unroll
    for (int j = 0; j < 4; j++) acc[i][j] = 0.0f;

  for (int kk = 0; kk < K; kk += 32) {
    __syncthreads();
    #pragma unroll
    for (int s = 0; s < 2; s++) {
      const int bu = s * 256 + w * 64;
      const int unit = bu + lane;
      const int row = unit >> 2, ch = unit & 3;
      async_copy16(A + (size_t)(m0 + row) * K + kk + ch * 8, (char*)As + bu * 16);
      async_copy16(BT + (size_t)(n0 + row) * K + kk + ch * 8, (char*)Bs + bu * 16);
    }
    __syncthreads();
    bf8_t a[4], b[4];
    #pragma unroll
    for (int mi = 0; mi < 4; mi++)
      a[mi] = *(const bf8_t*)(As + (wr * 64 + mi * 16 + l15) * 32 + l4 * 8);
    #pragma unroll
    for (int ni = 0; ni < 4; ni++)
      b[ni] = *(const bf8_t*)(Bs + (wc * 64 + ni * 16 + l15) * 32 + l4 * 8);
    #pragma unroll
    for (int mi = 0; mi < 4; mi++)
      #pragma unroll
      for (int ni = 0; ni < 4; ni++)
        acc[mi][ni] = __builtin_amdgcn_mfma_f32_16x16x32_bf16(a[mi], b[ni], acc[mi][ni], 0, 0, 0);
  }

  #pragma unroll
  for (int mi = 0; mi < 4; mi++) {
    #pragma unroll
    for (int ni = 0; ni < 4; ni++) {
      #pragma unroll
      for (int r = 0; r < 4; r++) {
        const int row = m0 + wr * 64 + mi * 16 + l4 * 4 + r;
        const int col = n0 + wc * 64 + ni * 16 + l15;
        gemm_epi(EPI, Cout, RES, (size_t)row * N + col, acc[mi][ni][r]);
      }
    }
  }
}

// ---------- 128x64-tile GEMM for N=2048 outputs (proj / mlp_proj) ----------
// Same m97 schedule, smaller tile: grid = (N/64)*(M/128) = 512 blocks -> 2+/CU
// (the 128^2 tile gives only 256 blocks = 1/CU = m102's starved 320 TF regime).
// 4 waves, each owns 32 rows x 64 cols (acc 2x4). LDS 12 KB.
template <int EPI>
__global__ __launch_bounds__(256, 3) void gemm_bt64(const uint16_t* __restrict__ A,
                                                    const uint16_t* __restrict__ BT,
                                                    void* __restrict__ Cout,
                                                    const void* __restrict__ RES,
                                                    int M, int N, int K) {
  __shared__ uint16_t As[128 * 32];  // 8 KB
  __shared__ uint16_t Bs[64 * 32];   // 4 KB
  const int tid = threadIdx.x;
  const int lane = tid & 63;
  const int w = tid >> 6;
  const int l15 = lane & 15, l4 = lane >> 4;
  const int m0 = blockIdx.y * 128, n0 = blockIdx.x * 64;

  f32x4 acc[2][4];
  #pragma unroll
  for (int i = 0; i < 2; i++)
    #pragma unroll
    for (int j = 0; j < 4; j++) acc[i][j] = 0.0f;

  for (int kk = 0; kk < K; kk += 32) {
    __syncthreads();
    // A: 512 16B-units (2 per thread)
    #pragma unroll
    for (int s = 0; s < 2; s++) {
      const int bu = s * 256 + w * 64;
      const int unit = bu + lane;
      const int row = unit >> 2, ch = unit & 3;
      async_copy16(A + (size_t)(m0 + row) * K + kk + ch * 8, (char*)As + bu * 16);
    }
    // B: 256 16B-units (1 per thread)
    {
      const int bu = w * 64;
      const int unit = bu + lane;
      const int row = unit >> 2, ch = unit & 3;
      async_copy16(BT + (size_t)(n0 + row) * K + kk + ch * 8, (char*)Bs + bu * 16);
    }
    __syncthreads();
    bf8_t a[2], b[4];
    #pragma unroll
    for (int mi = 0; mi < 2; mi++)
      a[mi] = *(const bf8_t*)(As + (w * 32 + mi * 16 + l15) * 32 + l4 * 8);
    #pragma unroll
    for (int ni = 0; ni < 4; ni++)
      b[ni] = *(const bf8_t*)(Bs + (ni * 16 + l15) * 32 + l4 * 8);
    #pragma unroll
    for (int mi = 0; mi < 2; mi++)
      #pragma unroll
      for (int ni = 0; ni < 4; ni++)
        acc[mi][ni] = __builtin_amdgcn_mfma_f32_16x16x32_bf16(a[mi], b[ni], acc[mi][ni], 0, 0, 0);
  }

  #pragma unroll
  for (int mi = 0; mi < 2; mi++) {
    #pragma unroll
    for (int ni = 0; ni < 4; ni++) {
      #pragma unroll
      for (int r = 0; r < 4; r++) {
        const int row = m0 + w * 32 + mi * 16 + l4 * 4 + r;
        const int col = n0 + ni * 16 + l15;
        gemm_epi(EPI, Cout, RES, (size_t)row * N + col, acc[mi][ni][r]);
      }
    }
  }
}

// ---------- flash attention with alibi + causal (unchanged) ----------
__global__ __launch_bounds__(256, 2) void attn_kernel(const uint16_t* __restrict__ qkv,
                                                      const uint16_t* __restrict__ vT,
                                                      const float* __restrict__ alibi,
                                                      uint16_t* __restrict__ Y) {
  const int h = blockIdx.y;
  const int qt = 31 - blockIdx.x;
  const int tid = threadIdx.x;
  const int lane = tid & 63;
  const int w = tid >> 6;
  const int l15 = lane & 15, l4 = lane >> 4;

  __shared__ uint16_t Ks[2][64 * 128];
  __shared__ uint16_t Vs[2][128 * 64];
  __shared__ uint16_t Ps[4][16 * 64];

  const float scale = 0.08838834764831845f;

  auto stage = [&](int kv0, int b) {
    #pragma unroll
    for (int i = 0; i < 4; i++) {
      const int u = tid + i * 256;
      const int r = u >> 4;
      const int c = (u & 15) ^ ((r & 7) ^ ((r >> 3) & 7));
      async_copy16(qkv + (size_t)(kv0 + r) * 6144 + 2048 + h * 128 + c * 8,
                   (char*)Ks[b] + u * 16);
    }
    #pragma unroll
    for (int i = 0; i < 4; i++) {
      const int u = tid + i * 256;
      const int r = u >> 3;
      const int c = (u & 7) ^ (r & 7);
      async_copy16(vT + (size_t)(h * 128 + r) * 2048 + kv0 + c * 8,
                   (char*)Vs[b] + u * 16);
    }
  };
  auto load_al = [&](int kv0, float (&al)[4][4]) {
    #pragma unroll
    for (int r = 0; r < 4; r++) {
      const size_t rowb = ((size_t)h * 2048 + (qt * 64 + w * 16 + l4 * 4 + r)) * 2048;
      #pragma unroll
      for (int nf = 0; nf < 4; nf++)
        al[nf][r] = alibi[rowb + kv0 + nf * 16 + l15];
    }
  };

  const int qrow = qt * 64 + w * 16 + l15;
  bf8_t qf[4];
  #pragma unroll
  for (int kc = 0; kc < 4; kc++)
    qf[kc] = *(const bf8_t*)(qkv + (size_t)qrow * 6144 + h * 128 + kc * 32 + l4 * 8);

  f32x4 accy[8];
  #pragma unroll
  for (int i = 0; i < 8; i++) accy[i] = 0.0f;
  float mrun[4], lrun[4];
  #pragma unroll
  for (int r = 0; r < 4; r++) { mrun[r] = -1e30f; lrun[r] = 0.0f; }

  stage(0, 0);
  float al[4][4];
  load_al(0, al);

  for (int kvt = 0; kvt <= qt; kvt++) {
    const int b = kvt & 1;
    const int kv0 = kvt * 64;
    __syncthreads();

    const int kvn = (kvt < qt) ? (kvt + 1) : qt;
    float aln[4][4];
    load_al(kvn * 64, aln);
    stage(kvn * 64, b ^ 1);

    float s[4][4];
    #pragma unroll
    for (int nf = 0; nf < 4; nf++) {
      f32x4 sa = 0.0f;
      const int krow = nf * 16 + l15;
      #pragma unroll
      for (int kc = 0; kc < 4; kc++) {
        bf8_t kb = *(const bf8_t*)((const char*)Ks[b] +
                                   ((krow * 256 + kc * 64 + l4 * 16) ^ swz(krow)));
        sa = __builtin_amdgcn_mfma_f32_16x16x32_bf16(qf[kc], kb, sa, 0, 0, 0);
      }
      const int kvcol = kv0 + nf * 16 + l15;
      #pragma unroll
      for (int r = 0; r < 4; r++) {
        const int q = qt * 64 + w * 16 + l4 * 4 + r;
        float sv = sa[r] * scale + al[nf][r];
        if (kvcol > q) sv = -1e30f;
        s[nf][r] = sv;
      }
    }

    #pragma unroll
    for (int r = 0; r < 4; r++) {
      float rm = fmaxf(fmaxf(s[0][r], s[1][r]), fmaxf(s[2][r], s[3][r]));
      rm = fmaxf(rm, __shfl_xor(rm, 1));
      rm = fmaxf(rm, __shfl_xor(rm, 2));
      rm = fmaxf(rm, __shfl_xor(rm, 4));
      rm = fmaxf(rm, __shfl_xor(rm, 8));
      const float mnew = fmaxf(mrun[r], rm);
      const float alpha = __expf(mrun[r] - mnew);
      mrun[r] = mnew;
      float rs = 0.0f;
      #pragma unroll
      for (int nf = 0; nf < 4; nf++) {
        const float p = __expf(s[nf][r] - mnew);
        s[nf][r] = p;
        rs += p;
      }
      rs += __shfl_xor(rs, 1);
      rs += __shfl_xor(rs, 2);
      rs += __shfl_xor(rs, 4);
      rs += __shfl_xor(rs, 8);
      lrun[r] = lrun[r] * alpha + rs;
      #pragma unroll
      for (int df = 0; df < 8; df++) accy[df][r] *= alpha;
    }

    #pragma unroll
    for (int nf = 0; nf < 4; nf++) {
      #pragma unroll
      for (int r = 0; r < 4; r++) {
        const int rq = l4 * 4 + r;
        const int bo = (rq * 128 + (nf * 16 + l15) * 2) ^ vswz(rq);
        *(uint16_t*)((char*)Ps[w] + bo) = f2bf(s[nf][r]);
      }
    }

    #pragma unroll
    for (int kk = 0; kk < 2; kk++) {
      bf8_t pa = *(const bf8_t*)((const char*)Ps[w] +
                                 ((l15 * 128 + kk * 64 + l4 * 16) ^ vswz(l15)));
      #pragma unroll
      for (int df = 0; df < 8; df++) {
        const int vr = df * 16 + l15;
        bf8_t vb = *(const bf8_t*)((const char*)Vs[b] +
                                   ((vr * 128 + kk * 64 + l4 * 16) ^ vswz(vr)));
        accy[df] = __builtin_amdgcn_mfma_f32_16x16x32_bf16(pa, vb, accy[df], 0, 0, 0);
      }
    }

    #pragma unroll
    for (int nf = 0; nf < 4; nf++)
      #pragma unroll
      for (int r = 0; r < 4; r++) al[nf][r] = aln[nf][r];
  }

  #pragma unroll
  for (int df = 0; df < 8; df++) {
    #pragma unroll
    for (int r = 0; r < 4; r++) {
      const int row = qt * 64 + w * 16 + l4 * 4 + r;
      const int col = h * 128 + df * 16 + l15;
      Y[(size_t)row * 2048 + col] = f2bf(accy[df][r] / lrun[r]);
    }
  }
}

// ---------- launch ----------
extern "C" void kernel_launch(void* const* d_in, const int* in_sizes, int n_in,
                              void* d_out, int out_size, void* d_ws, size_t ws_size,
                              hipStream_t stream) {
  const float* x      = (const float*)d_in[0];
  const float* alibi  = (const float*)d_in[1];
  const float* w_attn = (const float*)d_in[2];
  const float* w_proj = (const float*)d_in[3];
  const float* w_fc1  = (const float*)d_in[4];
  const float* w_fc2  = (const float*)d_in[5];
  const float* w_mp   = (const float*)d_in[6];
  const float* rms1   = (const float*)d_in[7];
  const float* rms2   = (const float*)d_in[8];
  float* out = (float*)d_out;

  char* ws = (char*)d_ws;
  uint16_t* xn      = (uint16_t*)(ws + 0);
  uint16_t* qkv     = (uint16_t*)(ws + 8388608);
  uint16_t* y       = (uint16_t*)(ws + 33554432);
  uint16_t* g1      = (uint16_t*)(ws + 41943040);
  uint16_t* hbuf    = (uint16_t*)(ws + 65011712);
  uint16_t* wt_attn = (uint16_t*)(ws + 88080384);
  uint16_t* wt_proj = (uint16_t*)(ws + 113246208);
  uint16_t* wt_fc1  = (uint16_t*)(ws + 121634816);
  uint16_t* wt_fc2  = (uint16_t*)(ws + 144703488);
  uint16_t* wt_mp   = (uint16_t*)(ws + 167772160);
  uint16_t* vT      = (uint16_t*)(ws + 190840832);

  transpose_conv<<<dim3(6144 / 64, 2048 / 64), 256, 0, stream>>>(w_attn, wt_attn, 2048, 6144);
  transpose_conv<<<dim3(2048 / 64, 2048 / 64), 256, 0, stream>>>(w_proj, wt_proj, 2048, 2048);
  transpose_conv<<<dim3(5632 / 64, 2048 / 64), 256, 0, stream>>>(w_fc1, wt_fc1, 2048, 5632);
  transpose_conv<<<dim3(5632 / 64, 2048 / 64), 256, 0, stream>>>(w_fc2, wt_fc2, 2048, 5632);
  transpose_conv<<<dim3(2048 / 64, 5632 / 64), 256, 0, stream>>>(w_mp, wt_mp, 5632, 2048);

  rmsnorm_kernel<<<2048, 256, 0, stream>>>(x, rms1, xn);

  gemm_bt<EPI_BF16><<<dim3(6144 / 128, 2048 / 128), 256, 0, stream>>>(
      xn, wt_attn, qkv, nullptr, 2048, 6144, 2048);

  transpose_v<<<dim3(32, 32), 256, 0, stream>>>(qkv, vT);

  attn_kernel<<<dim3(32, 16), 256, 0, stream>>>(qkv, vT, alibi, y);

  gemm_bt64<EPI_ADDF32><<<dim3(2048 / 64, 2048 / 128), 256, 0, stream>>>(
      y, wt_proj, out, x, 2048, 2048, 2048);

  rmsnorm_kernel<<<2048, 256, 0, stream>>>(out, rms2, xn);

  gemm_bt<EPI_BF16><<<dim3(5632 / 128, 2048 / 128), 256, 0, stream>>>(
      xn, wt_fc1, g1, nullptr, 2048, 5632, 2048);

  gemm_bt<EPI_SILUMUL><<<dim3(5632 / 128, 2048 / 128), 256, 0, stream>>>(
      xn, wt_fc2, hbuf, g1, 2048, 5632, 2048);

  gemm_bt64<EPI_ADDF32><<<dim3(2048 / 64, 2048 / 128), 256, 0, stream>>>(
      hbuf, wt_mp, out, out, 2048, 2048, 5632);
}